// Round 2
// baseline (42.968 us; speedup 1.0000x reference)
//
#include <hip/hip_runtime.h>
#include <float.h>

#define BT 8
#define NV 10000
#define NB 16384
#define NS 4096
#define NPTS (BT * NS)                  // 32768 boundary points
#define PTS_PER_BLOCK 1024              // 256 threads * 4 points
#define SBLOCKS (NPTS / PTS_PER_BLOCK)  // 32
#define TILE 2048                       // verts per LDS tile (32KB of float4)

// Stage 1: partial min over a vertex chunk for 4 points/thread.
// grid.x = SBLOCKS * vchunks; block = 256
__global__ void __launch_bounds__(256, 4)
stage1(const float* __restrict__ verts, const float4* __restrict__ bds4,
       const int* __restrict__ idx, float* __restrict__ pmin,
       int vchunks, int ch) {
    __shared__ float4 sv[TILE];
    const int sblk  = blockIdx.x % SBLOCKS;
    const int chunk = blockIdx.x / SBLOCKS;
    const int b  = sblk * PTS_PER_BLOCK / NS;   // block lies within one batch
    const int p0 = sblk * PTS_PER_BLOCK;
    const int v0 = chunk * ch;
    const int vend = (v0 + ch < NV) ? (v0 + ch) : NV;

    float bx[4], by[4], bz[4], m[4];
#pragma unroll
    for (int k = 0; k < 4; ++k) {
        int pt = p0 + threadIdx.x + k * 256;
        int s = pt & (NS - 1);
        int j = idx[s];
        float4 bp = bds4[(size_t)b * NB + j];
        bx[k] = bp.x; by[k] = bp.y; bz[k] = bp.z;
        m[k] = FLT_MAX;
    }

    for (int t0 = v0; t0 < vend; t0 += TILE) {
        int tn = (TILE < vend - t0) ? TILE : (vend - t0);
        __syncthreads();
        for (int i = threadIdx.x; i < tn; i += 256) {
            const float* vp = verts + (size_t)(b * NV + t0 + i) * 3;
            float x = vp[0], y = vp[1], z = vp[2];
            sv[i] = make_float4(-2.0f * x, -2.0f * y, -2.0f * z,
                                x * x + y * y + z * z);
        }
        __syncthreads();
#pragma unroll 4
        for (int v = 0; v < tn; ++v) {
            float4 q = sv[v];  // broadcast read, conflict-free
#pragma unroll
            for (int k = 0; k < 4; ++k) {
                float t = fmaf(bx[k], q.x, fmaf(by[k], q.y, fmaf(bz[k], q.z, q.w)));
                m[k] = fminf(m[k], t);
            }
        }
    }

#pragma unroll
    for (int k = 0; k < 4; ++k) {
        int pt = p0 + threadIdx.x + k * 256;
        pmin[(size_t)chunk * NPTS + pt] = m[k];
    }
}

// Stage 2: combine chunk mins, add sq_b, apply mask, per-block sum.
// grid = 128 blocks * 256 threads = 32768 points
__global__ void stage2(const float* __restrict__ pmin, const float4* __restrict__ bds4,
                       const int* __restrict__ idx, float* __restrict__ bsum,
                       int vchunks) {
    int pt = blockIdx.x * 256 + threadIdx.x;
    int b = pt >> 12;           // / NS
    int s = pt & (NS - 1);
    int j = idx[s];
    float4 bp = bds4[(size_t)b * NB + j];
    float md = FLT_MAX;
    for (int c = 0; c < vchunks; ++c)
        md = fminf(md, pmin[(size_t)c * NPTS + pt]);
    float sqb = bp.x * bp.x + bp.y * bp.y + bp.z * bp.z;
    float val = (md + sqb) * bp.w * (1.0f / (float)NPTS);

    // block reduction (4 waves of 64)
    for (int o = 32; o > 0; o >>= 1) val += __shfl_down(val, o, 64);
    __shared__ float red[4];
    if ((threadIdx.x & 63) == 0) red[threadIdx.x >> 6] = val;
    __syncthreads();
    if (threadIdx.x == 0) bsum[blockIdx.x] = red[0] + red[1] + red[2] + red[3];
}

// Stage 3: final sum of 128 block partials -> scalar
__global__ void stage3(const float* __restrict__ bsum, float* __restrict__ out) {
    float v = bsum[threadIdx.x];  // 128 threads
    for (int o = 32; o > 0; o >>= 1) v += __shfl_down(v, o, 64);
    __shared__ float r[2];
    if ((threadIdx.x & 63) == 0) r[threadIdx.x >> 6] = v;
    __syncthreads();
    if (threadIdx.x == 0) out[0] = r[0] + r[1];
}

extern "C" void kernel_launch(void* const* d_in, const int* in_sizes, int n_in,
                              void* d_out, int out_size, void* d_ws, size_t ws_size,
                              hipStream_t stream) {
    const float*  verts = (const float*)d_in[0];
    const float4* bds4  = (const float4*)d_in[1];  // (BT, NB, 4) rows
    const int*    idx   = (const int*)d_in[3];     // int32 per harness convention
    float* out = (float*)d_out;

    char* ws = (char*)d_ws;
    size_t per_chunk = (size_t)NPTS * sizeof(float);   // 128 KB of partial mins
    size_t rem = (ws_size > 4096) ? (ws_size - 4096) : 0;
    int vchunks = (int)(rem / per_chunk);
    if (vchunks > 32) vchunks = 32;
    if (vchunks < 1)  vchunks = 1;
    float* pmin = (float*)ws;
    float* bsum = (float*)(ws + (size_t)vchunks * per_chunk);  // 128 floats

    int ch = (NV + vchunks - 1) / vchunks;

    stage1<<<SBLOCKS * vchunks, 256, 0, stream>>>(verts, bds4, idx, pmin, vchunks, ch);
    stage2<<<NPTS / 256, 256, 0, stream>>>(pmin, bds4, idx, bsum, vchunks);
    stage3<<<1, 128, 0, stream>>>(bsum, out);
}